// Round 2
// baseline (104.623 us; speedup 1.0000x reference)
//
#include <hip/hip_runtime.h>
#include <math.h>

// Problem constants (from reference)
#define SPIN 365
#define TRAINL 200000

#define THREADS 256
#define ITEMS 4
#define CHUNK (THREADS * ITEMS)  // 1024 elements per block
// B = 262144 -> G = 256 blocks; all co-resident on 256 CUs (grid barrier safe).
// Phase-B LDS scan assumes G <= THREADS.

struct Sc { float oo, oogw, ol1, b0, wb2; };

__device__ __forceinline__ Sc get_sc(const float* w0, const float* w1,
                                     const float* w2, const float* w3,
                                     const float* b0p, const float* wb2p) {
  float e_om = expf(w0[0]);
  float e_gw = expf(w1[0]);
  float e_lm = expf(w2[0]);
  float e_fm = expf(w3[0]);
  float denom = e_om + e_gw + e_lm + e_fm;
  Sc s;
  s.oo   = e_om / denom;
  s.oogw = e_gw / denom;
  s.ol1  = e_lm / denom;
  s.b0   = b0p[0];
  s.wb2  = wb2p[0];
  return s;
}

__device__ __forceinline__ float sigm(float z) { return 1.0f / (1.0f + expf(-z)); }

// ws float layout:
// [0,G)     block aggregate P
// [G,2G)    block aggregate Q
// [2G,3G)   block partial sum   of y_obs[SPIN:TRAINL]
// [3G,4G)   block partial sumsq of y_obs[SPIN:TRAINL]
// [4G]      (as uint) grid-barrier counter — zeroed by hipMemsetAsync each launch

extern "C" __global__ __launch_bounds__(THREADS) void k_fused(
    const float* __restrict__ x, const float* __restrict__ y,
    const int* __restrict__ tlp,
    const float* __restrict__ w0, const float* __restrict__ w1,
    const float* __restrict__ w2, const float* __restrict__ w3,
    const float* __restrict__ b0p, const float* __restrict__ wb2p,
    float* __restrict__ out, float* __restrict__ ws,
    unsigned int* __restrict__ cnt, int B, int G)
{
  const int g = blockIdx.x, tid = threadIdx.x;
  const int tl = tlp[0];
  const Sc sc = get_sc(w0, w1, w2, w3, b0p, wb2p);
  const int base = g * CHUNK + tid * ITEMS;
  const bool full = (base + ITEMS) <= B;

  // ---- load x once; keep everything in registers across the barrier ----
  float u1v[ITEMS], u2v[ITEMS];
  if (full) {
    float4 a = *(const float4*)(x + 2 * (size_t)base);
    float4 b = *(const float4*)(x + 2 * (size_t)base + 4);
    u1v[0]=a.x; u2v[0]=a.y; u1v[1]=a.z; u2v[1]=a.w;
    u1v[2]=b.x; u2v[2]=b.y; u1v[3]=b.z; u2v[3]=b.w;
  } else {
    for (int j = 0; j < ITEMS; j++) {
      int p = base + j;
      u1v[j] = (p < B) ? x[2*(size_t)p]     : 0.f;
      u2v[j] = (p < B) ? x[2*(size_t)p + 1] : 0.f;
    }
  }

  float P = 1.f, Q = 0.f;
  float olv[ITEMS], fv[ITEMS];
  for (int j = 0; j < ITEMS; j++) {
    int p = base + j;
    float ol = sc.ol1 * sigm(sc.b0 + (u2v[j] - 2.9086f) / 1.898f * sc.wb2);
    float f  = 1.0f - sc.oo - ol - sc.oogw;
    olv[j] = ol; fv[j] = f;
    bool act = (p >= tl) && (p < B);
    if (act) { Q = f * Q + u1v[j]; P *= f; }
  }

  // ---- c-independent outputs (overlap with barrier latency) ----
  if (full) {
    float voo[ITEMS], vgw[ITEMS], vol[ITEMS], vf[ITEMS];
    for (int j = 0; j < ITEMS; j++) {
      int p = base + j;
      bool act = (p >= tl);
      voo[j] = act ? sc.oo   : 0.f;
      vgw[j] = act ? sc.oogw : 0.f;
      vol[j] = act ? olv[j]  : 0.f;
      vf[j]  = act ? fv[j]   : 0.f;
    }
    *(float4*)(out + 4*(size_t)B + base) = make_float4(0,0,0,0);                       // bp_n
    *(float4*)(out + 5*(size_t)B + base) = make_float4(0,0,0,0);                       // gate_ib
    *(float4*)(out + 6*(size_t)B + base) = make_float4(voo[0],voo[1],voo[2],voo[3]);   // gate_oo
    *(float4*)(out + 7*(size_t)B + base) = make_float4(vgw[0],vgw[1],vgw[2],vgw[3]);   // gate_oogw
    *(float4*)(out + 8*(size_t)B + base) = make_float4(vol[0],vol[1],vol[2],vol[3]);   // gate_ol
    *(float4*)(out + 9*(size_t)B + base) = make_float4(vf[0],vf[1],vf[2],vf[3]);       // gate_f
  } else {
    for (int j = 0; j < ITEMS; j++) {
      int p = base + j;
      if (p < B) {
        bool act = (p >= tl);
        out[4*(size_t)B+p] = 0.f;                     out[5*(size_t)B+p] = 0.f;
        out[6*(size_t)B+p] = act ? sc.oo   : 0.f;     out[7*(size_t)B+p] = act ? sc.oogw : 0.f;
        out[8*(size_t)B+p] = act ? olv[j]  : 0.f;     out[9*(size_t)B+p] = act ? fv[j]   : 0.f;
      }
    }
  }

  // ---- block-level scan of affine pairs ----
  __shared__ float sA[THREADS], sB[THREADS];
  sA[tid] = P; sB[tid] = Q;
  __syncthreads();
  for (int off = 1; off < THREADS; off <<= 1) {
    float a = sA[tid], b = sB[tid];
    float pa = 1.f, pb = 0.f;
    if (tid >= off) { pa = sA[tid - off]; pb = sB[tid - off]; }
    __syncthreads();
    sA[tid] = pa * a;
    sB[tid] = a * pb + b;
    __syncthreads();
  }
  float Ae = 1.f, Be = 0.f;                 // thread-exclusive prefix within block
  if (tid > 0) { Ae = sA[tid - 1]; Be = sB[tid - 1]; }
  if (tid == THREADS - 1) { ws[g] = sA[tid]; ws[G + g] = sB[tid]; }  // block aggregate
  __syncthreads();

  // ---- y_obs partial sums ----
  float s = 0.f, ss = 0.f;
  if (base < TRAINL) {
    if (full) {
      float4 yv = *(const float4*)(y + base);
      float vv[4] = { yv.x, yv.y, yv.z, yv.w };
      for (int j = 0; j < ITEMS; j++) {
        int p = base + j;
        if (p >= SPIN && p < TRAINL) { s += vv[j]; ss += vv[j]*vv[j]; }
      }
    } else {
      for (int j = 0; j < ITEMS; j++) {
        int p = base + j;
        if (p >= SPIN && p < TRAINL && p < B) { float v = y[p]; s += v; ss += v*v; }
      }
    }
  }
  sA[tid] = s; sB[tid] = ss;
  __syncthreads();
  for (int off = THREADS/2; off > 0; off >>= 1) {
    if (tid < off) { sA[tid] += sA[tid + off]; sB[tid] += sB[tid + off]; }
    __syncthreads();
  }
  if (tid == 0) { ws[2*G + g] = sA[0]; ws[3*G + g] = sB[0]; }

  // ---- grid barrier (all 256 blocks co-resident) ----
  __threadfence();                           // flush this thread/block's ws writes
  __syncthreads();
  if (tid == 0) {
    __hip_atomic_fetch_add(cnt, 1u, __ATOMIC_ACQ_REL, __HIP_MEMORY_SCOPE_AGENT);
    while (__hip_atomic_load(cnt, __ATOMIC_ACQUIRE, __HIP_MEMORY_SCOPE_AGENT) < (unsigned)G) {
      __builtin_amdgcn_s_sleep(2);
    }
  }
  __syncthreads();

  // ---- phase B: every block redundantly scans the G aggregates ----
  float aP = 1.f, aQ = 0.f, yS = 0.f, ySS = 0.f;
  if (tid < G) {
    aP  = __hip_atomic_load(&ws[tid],       __ATOMIC_RELAXED, __HIP_MEMORY_SCOPE_AGENT);
    aQ  = __hip_atomic_load(&ws[G + tid],   __ATOMIC_RELAXED, __HIP_MEMORY_SCOPE_AGENT);
    yS  = __hip_atomic_load(&ws[2*G + tid], __ATOMIC_RELAXED, __HIP_MEMORY_SCOPE_AGENT);
    ySS = __hip_atomic_load(&ws[3*G + tid], __ATOMIC_RELAXED, __HIP_MEMORY_SCOPE_AGENT);
  }
  sA[tid] = aP; sB[tid] = aQ;
  __syncthreads();
  for (int off = 1; off < THREADS; off <<= 1) {
    float a = sA[tid], b = sB[tid];
    float pa = 1.f, pb = 0.f;
    if (tid >= off) { pa = sA[tid - off]; pb = sB[tid - off]; }
    __syncthreads();
    sA[tid] = pa * a;
    sB[tid] = a * pb + b;
    __syncthreads();
  }
  const float Cg = (g == 0) ? 0.f : sB[g - 1];   // carry into this block (c0 = 0)
  __syncthreads();

  // redundant (deterministic) obsstd reduction
  sA[tid] = yS; sB[tid] = ySS;
  __syncthreads();
  for (int off = THREADS/2; off > 0; off >>= 1) {
    if (tid < off) { sA[tid] += sA[tid + off]; sB[tid] += sB[tid + off]; }
    __syncthreads();
  }
  float ostd;
  {
    float n = (float)(TRAINL - SPIN);
    float S = sA[0], SS = sB[0];
    float mean = S / n;
    float var = (SS - n * mean * mean) / (n - 1.0f);
    ostd = sqrtf(fmaxf(var, 0.f));
  }

  // ---- c-dependent outputs ----
  float c = Ae * Cg + Be;                    // c at this thread's first element
  float vh[ITEMS], vc[ITEMS], vl[ITEMS], vgw[ITEMS], vos[ITEMS];
  for (int j = 0; j < ITEMS; j++) {
    int p = base + j;
    bool act = (p >= tl) && (p < B);
    float c0 = c;                            // scan emits c BEFORE this step
    vh[j]  = sc.oo * c0;
    vc[j]  = c0;
    vl[j]  = olv[j] * c0;
    vgw[j] = sc.oogw * c0;
    vos[j] = act ? ostd : 0.f;
    if (act) { c = fv[j] * c + u1v[j]; }
  }

  if (full) {
    *(float4*)(out + (size_t)base)        = make_float4(vh[0],vh[1],vh[2],vh[3]);     // h_n
    *(float4*)(out + (size_t)B + base)    = make_float4(vc[0],vc[1],vc[2],vc[3]);     // c_n
    *(float4*)(out + 2*(size_t)B + base)  = make_float4(vl[0],vl[1],vl[2],vl[3]);     // l_n
    *(float4*)(out + 3*(size_t)B + base)  = make_float4(vgw[0],vgw[1],vgw[2],vgw[3]); // gw_n
    *(float4*)(out + 12*(size_t)B + base) = make_float4(vos[0],vos[1],vos[2],vos[3]); // obs_std
    // h_nout: (B,2) row-major [h, obsstd]
    *(float4*)(out + 10*(size_t)B + 2*base)     = make_float4(vh[0],vos[0],vh[1],vos[1]);
    *(float4*)(out + 10*(size_t)B + 2*base + 4) = make_float4(vh[2],vos[2],vh[3],vos[3]);
  } else {
    for (int j = 0; j < ITEMS; j++) {
      int p = base + j;
      if (p < B) {
        out[(size_t)p]            = vh[j];
        out[(size_t)B + p]        = vc[j];
        out[2*(size_t)B + p]      = vl[j];
        out[3*(size_t)B + p]      = vgw[j];
        out[12*(size_t)B + p]     = vos[j];
        out[10*(size_t)B + 2*p]     = vh[j];
        out[10*(size_t)B + 2*p + 1] = vos[j];
      }
    }
  }
}

extern "C" void kernel_launch(void* const* d_in, const int* in_sizes, int n_in,
                              void* d_out, int out_size, void* d_ws, size_t ws_size,
                              hipStream_t stream) {
  const float* x   = (const float*)d_in[0];
  const float* y   = (const float*)d_in[1];
  // d_in[2] = epoch (unused)
  const int*   tl  = (const int*)d_in[3];
  const float* w0  = (const float*)d_in[4];  // weight_r_yom
  const float* w1  = (const float*)d_in[5];  // weight_r_yom_gw
  const float* w2  = (const float*)d_in[6];  // weight_r_ylm
  const float* w3  = (const float*)d_in[7];  // weight_r_yfm
  const float* b0  = (const float*)d_in[8];  // bias_b0_ylm
  const float* wb2 = (const float*)d_in[9];  // weight_b2_ylm

  float* out = (float*)d_out;
  float* ws  = (float*)d_ws;

  const int B = in_sizes[0] / 2;            // x is (B, 1, 2)
  const int G = (B + CHUNK - 1) / CHUNK;    // 256 for B=262144

  unsigned int* cnt = (unsigned int*)(ws + 4 * (size_t)G);
  // zero the barrier counter each launch (graph-capturable memset node)
  hipMemsetAsync(cnt, 0, sizeof(unsigned int), stream);

  k_fused<<<G, THREADS, 0, stream>>>(x, y, tl, w0, w1, w2, w3, b0, wb2,
                                     out, ws, cnt, B, G);
}

// Round 4
// 80.310 us; speedup vs baseline: 1.3027x; 1.3027x over previous
//
#include <hip/hip_runtime.h>
#include <math.h>

// Problem constants (from reference)
#define SPIN 365
#define TRAINL 200000
#define ML 2.9086f
#define SLINV (1.0f / 1.898f)

#define THREADS 512            // 8 waves/block
#define ITEMS 2
#define CHUNK (THREADS * ITEMS)  // 1024 elements/block
#define NW (THREADS / 64)        // waves per block
// B = 262144 -> G = 256 blocks. k2's LDS aggregate scan assumes G <= THREADS.

struct Sc { float oo, oogw, ol1, b0, k; };

__device__ __forceinline__ Sc get_sc(const float* w0, const float* w1,
                                     const float* w2, const float* w3,
                                     const float* b0p, const float* wb2p) {
  float e_om = __expf(w0[0]);
  float e_gw = __expf(w1[0]);
  float e_lm = __expf(w2[0]);
  float e_fm = __expf(w3[0]);
  float denom = e_om + e_gw + e_lm + e_fm;
  Sc s;
  s.oo   = e_om / denom;
  s.oogw = e_gw / denom;
  s.ol1  = e_lm / denom;
  s.b0   = b0p[0];
  s.k    = wb2p[0] * SLINV;
  return s;
}

__device__ __forceinline__ float sigm_fast(float z) {
  return __fdividef(1.0f, 1.0f + __expf(-z));
}

// ws float layout:
// [0,G)     block aggregate P
// [G,2G)    block aggregate Q
// [2G,3G)   block partial sum   of y_obs[SPIN:TRAINL]
// [3G,4G)   block partial sumsq of y_obs[SPIN:TRAINL]

// ---------------- k1: per-block affine reduce + y partials + c-independent outs ----
extern "C" __global__ __launch_bounds__(THREADS) void k1(
    const float* __restrict__ x, const float* __restrict__ y,
    const int* __restrict__ tlp,
    const float* __restrict__ w0, const float* __restrict__ w1,
    const float* __restrict__ w2, const float* __restrict__ w3,
    const float* __restrict__ b0p, const float* __restrict__ wb2p,
    float* __restrict__ out, float* __restrict__ ws, int B, int G)
{
  const int g = blockIdx.x, tid = threadIdx.x;
  const int lane = tid & 63, wid = tid >> 6;
  const int tl = tlp[0];
  const Sc sc = get_sc(w0, w1, w2, w3, b0p, wb2p);
  const int base = g * CHUNK + tid * ITEMS;
  const bool full = (base + ITEMS) <= B;

  float u1v[ITEMS], u2v[ITEMS];
  if (full) {
    float4 a = *(const float4*)(x + 2 * (size_t)base);
    u1v[0] = a.x; u2v[0] = a.y; u1v[1] = a.z; u2v[1] = a.w;
  } else {
    for (int j = 0; j < ITEMS; j++) {
      int p = base + j;
      u1v[j] = (p < B) ? x[2*(size_t)p]     : 0.f;
      u2v[j] = (p < B) ? x[2*(size_t)p + 1] : 0.f;
    }
  }

  float P = 1.f, Q = 0.f;
  float olv[ITEMS], fv[ITEMS];
  for (int j = 0; j < ITEMS; j++) {
    int p = base + j;
    float ol = sc.ol1 * sigm_fast(sc.b0 + (u2v[j] - ML) * sc.k);
    float f  = 1.0f - sc.oo - ol - sc.oogw;
    olv[j] = ol; fv[j] = f;
    bool act = (p >= tl) && (p < B);
    if (act) { Q = f * Q + u1v[j]; P *= f; }
  }

  // c-independent outputs
  if (full) {
    bool a0 = (base >= tl), a1 = (base + 1 >= tl);
    *(float2*)(out + 4*(size_t)B + base) = make_float2(0.f, 0.f);                    // bp_n
    *(float2*)(out + 5*(size_t)B + base) = make_float2(0.f, 0.f);                    // gate_ib
    *(float2*)(out + 6*(size_t)B + base) = make_float2(a0?sc.oo:0.f,  a1?sc.oo:0.f);   // gate_oo
    *(float2*)(out + 7*(size_t)B + base) = make_float2(a0?sc.oogw:0.f,a1?sc.oogw:0.f); // gate_oogw
    *(float2*)(out + 8*(size_t)B + base) = make_float2(a0?olv[0]:0.f, a1?olv[1]:0.f);  // gate_ol
    *(float2*)(out + 9*(size_t)B + base) = make_float2(a0?fv[0]:0.f,  a1?fv[1]:0.f);   // gate_f
  } else {
    for (int j = 0; j < ITEMS; j++) {
      int p = base + j;
      if (p < B) {
        bool act = (p >= tl);
        out[4*(size_t)B+p] = 0.f;                  out[5*(size_t)B+p] = 0.f;
        out[6*(size_t)B+p] = act ? sc.oo   : 0.f;  out[7*(size_t)B+p] = act ? sc.oogw : 0.f;
        out[8*(size_t)B+p] = act ? olv[j]  : 0.f;  out[9*(size_t)B+p] = act ? fv[j]   : 0.f;
      }
    }
  }

  // order-preserving wave reduce of affine pairs (lane 0 gets wave aggregate)
  #pragma unroll
  for (int off = 1; off < 64; off <<= 1) {
    float pL = __shfl_down(P, off);
    float qL = __shfl_down(Q, off);
    Q = pL * Q + qL;   // combine(earlier=self, later=lane+off)
    P = pL * P;
  }

  // y_obs partials
  float s = 0.f, ss = 0.f;
  if (full && base < TRAINL) {
    float2 yv = *(const float2*)(y + base);
    float vv[2] = { yv.x, yv.y };
    for (int j = 0; j < ITEMS; j++) {
      int p = base + j;
      if (p >= SPIN && p < TRAINL) { s += vv[j]; ss += vv[j]*vv[j]; }
    }
  } else {
    for (int j = 0; j < ITEMS; j++) {
      int p = base + j;
      if (p >= SPIN && p < TRAINL && p < B) { float v = y[p]; s += v; ss += v*v; }
    }
  }
  #pragma unroll
  for (int off = 1; off < 64; off <<= 1) {
    s  += __shfl_xor(s,  off);
    ss += __shfl_xor(ss, off);
  }

  __shared__ float wA[NW], wB[NW], rS[NW], rSS[NW];
  if (lane == 0) { wA[wid] = P; wB[wid] = Q; rS[wid] = s; rSS[wid] = ss; }
  __syncthreads();
  if (tid == 0) {
    float A = 1.f, Bq = 0.f, S = 0.f, SS = 0.f;
    #pragma unroll
    for (int w = 0; w < NW; w++) {
      Bq = wA[w] * Bq + wB[w];   // compose earlier(prefix) then later(wave w)
      A  = wA[w] * A;
      S += rS[w]; SS += rSS[w];
    }
    ws[g] = A; ws[G + g] = Bq; ws[2*G + g] = S; ws[3*G + g] = SS;
  }
}

// ---------------- k2: redundant aggregate scan + std + c-dependent outputs ---------
extern "C" __global__ __launch_bounds__(THREADS) void k2(
    const float* __restrict__ x, const int* __restrict__ tlp,
    const float* __restrict__ w0, const float* __restrict__ w1,
    const float* __restrict__ w2, const float* __restrict__ w3,
    const float* __restrict__ b0p, const float* __restrict__ wb2p,
    float* __restrict__ out, const float* __restrict__ ws, int B, int G)
{
  const int g = blockIdx.x, tid = threadIdx.x;
  const int lane = tid & 63, wid = tid >> 6;
  const int tl = tlp[0];
  const Sc sc = get_sc(w0, w1, w2, w3, b0p, wb2p);
  const int base = g * CHUNK + tid * ITEMS;
  const bool full = (base + ITEMS) <= B;

  // own elements
  float u1v[ITEMS], u2v[ITEMS];
  if (full) {
    float4 a = *(const float4*)(x + 2 * (size_t)base);
    u1v[0] = a.x; u2v[0] = a.y; u1v[1] = a.z; u2v[1] = a.w;
  } else {
    for (int j = 0; j < ITEMS; j++) {
      int p = base + j;
      u1v[j] = (p < B) ? x[2*(size_t)p]     : 0.f;
      u2v[j] = (p < B) ? x[2*(size_t)p + 1] : 0.f;
    }
  }
  float P = 1.f, Q = 0.f;
  float olv[ITEMS], fv[ITEMS];
  for (int j = 0; j < ITEMS; j++) {
    int p = base + j;
    float ol = sc.ol1 * sigm_fast(sc.b0 + (u2v[j] - ML) * sc.k);
    float f  = 1.0f - sc.oo - ol - sc.oogw;
    olv[j] = ol; fv[j] = f;
    bool act = (p >= tl) && (p < B);
    if (act) { Q = f * Q + u1v[j]; P *= f; }
  }

  // wave-inclusive scan of own pairs
  float iP = P, iQ = Q;
  #pragma unroll
  for (int off = 1; off < 64; off <<= 1) {
    float pa = __shfl_up(iP, off);
    float pb = __shfl_up(iQ, off);
    if (lane >= off) { iQ = iP * pb + iQ; iP = iP * pa; }
  }

  // block aggregates + y partials from ws
  float aP  = (tid < G) ? ws[tid]       : 1.f;
  float aQ  = (tid < G) ? ws[G + tid]   : 0.f;
  float ys  = (tid < G) ? ws[2*G + tid] : 0.f;
  float yss = (tid < G) ? ws[3*G + tid] : 0.f;

  // wave-inclusive scan of aggregate pairs
  float jP = aP, jQ = aQ;
  #pragma unroll
  for (int off = 1; off < 64; off <<= 1) {
    float pa = __shfl_up(jP, off);
    float pb = __shfl_up(jQ, off);
    if (lane >= off) { jQ = jP * pb + jQ; jP = jP * pa; }
  }

  // y butterfly (all lanes get wave sum, bitwise identical)
  #pragma unroll
  for (int off = 1; off < 64; off <<= 1) {
    ys  += __shfl_xor(ys,  off);
    yss += __shfl_xor(yss, off);
  }

  __shared__ float wOA[NW], wOB[NW];     // own-scan wave aggregates
  __shared__ float wAA[NW], wAB[NW];     // aggregate-scan wave aggregates
  __shared__ float rS[NW], rSS[NW];
  __shared__ float sQ[THREADS];          // inclusive aggregate-scan Q
  if (lane == 63) { wOA[wid] = iP; wOB[wid] = iQ; wAA[wid] = jP; wAB[wid] = jQ; }
  if (lane == 0)  { rS[wid] = ys; rSS[wid] = yss; }
  __syncthreads();

  // exclusive wave prefixes (serial over <=8 LDS-broadcast entries)
  float OWA = 1.f, OWB = 0.f, AWA = 1.f, AWB = 0.f;
  for (int w = 0; w < wid; w++) {
    OWB = wOA[w] * OWB + wOB[w];  OWA = wOA[w] * OWA;
    AWB = wAA[w] * AWB + wAB[w];  AWA = wAA[w] * AWA;
  }
  // full inclusive aggregate-scan Q at this tid
  sQ[tid] = jP * AWB + jQ;

  // obsstd (every thread, identical order -> deterministic)
  float S = 0.f, SS = 0.f;
  #pragma unroll
  for (int w = 0; w < NW; w++) { S += rS[w]; SS += rSS[w]; }
  float n = (float)(TRAINL - SPIN);
  float mean = S / n;
  float var = (SS - n * mean * mean) / (n - 1.0f);
  float ostd = sqrtf(fmaxf(var, 0.f));
  __syncthreads();

  const float Cg = (g == 0) ? 0.f : sQ[g - 1];   // carry into this block (c0 = 0)

  // thread-exclusive prefix within block
  float eP = __shfl_up(iP, 1);
  float eQ = __shfl_up(iQ, 1);
  if (lane == 0) { eP = 1.f; eQ = 0.f; }
  float Ae = eP * OWA;
  float Be = eP * OWB + eQ;

  float c = Ae * Cg + Be;                 // c entering this thread's first element
  float vh[ITEMS], vc[ITEMS], vl[ITEMS], vgw[ITEMS], vos[ITEMS];
  for (int j = 0; j < ITEMS; j++) {
    int p = base + j;
    bool act = (p >= tl) && (p < B);
    float c0 = c;                         // scan emits c BEFORE this step
    vh[j]  = sc.oo * c0;
    vc[j]  = c0;
    vl[j]  = olv[j] * c0;
    vgw[j] = sc.oogw * c0;
    vos[j] = act ? ostd : 0.f;
    if (act) { c = fv[j] * c + u1v[j]; }
  }

  if (full) {
    *(float2*)(out + (size_t)base)        = make_float2(vh[0], vh[1]);    // h_n
    *(float2*)(out + (size_t)B + base)    = make_float2(vc[0], vc[1]);    // c_n
    *(float2*)(out + 2*(size_t)B + base)  = make_float2(vl[0], vl[1]);    // l_n
    *(float2*)(out + 3*(size_t)B + base)  = make_float2(vgw[0], vgw[1]);  // gw_n
    *(float2*)(out + 12*(size_t)B + base) = make_float2(vos[0], vos[1]);  // obs_std
    // h_nout: (B,2) row-major [h, obsstd] — one aligned float4 covers both items
    *(float4*)(out + 10*(size_t)B + 2*(size_t)base) = make_float4(vh[0], vos[0], vh[1], vos[1]);
  } else {
    for (int j = 0; j < ITEMS; j++) {
      int p = base + j;
      if (p < B) {
        out[(size_t)p]            = vh[j];
        out[(size_t)B + p]        = vc[j];
        out[2*(size_t)B + p]      = vl[j];
        out[3*(size_t)B + p]      = vgw[j];
        out[12*(size_t)B + p]     = vos[j];
        out[10*(size_t)B + 2*p]     = vh[j];
        out[10*(size_t)B + 2*p + 1] = vos[j];
      }
    }
  }
}

extern "C" void kernel_launch(void* const* d_in, const int* in_sizes, int n_in,
                              void* d_out, int out_size, void* d_ws, size_t ws_size,
                              hipStream_t stream) {
  const float* x   = (const float*)d_in[0];
  const float* y   = (const float*)d_in[1];
  // d_in[2] = epoch (unused)
  const int*   tl  = (const int*)d_in[3];
  const float* w0  = (const float*)d_in[4];  // weight_r_yom
  const float* w1  = (const float*)d_in[5];  // weight_r_yom_gw
  const float* w2  = (const float*)d_in[6];  // weight_r_ylm
  const float* w3  = (const float*)d_in[7];  // weight_r_yfm
  const float* b0  = (const float*)d_in[8];  // bias_b0_ylm
  const float* wb2 = (const float*)d_in[9];  // weight_b2_ylm

  float* out = (float*)d_out;
  float* ws  = (float*)d_ws;

  const int B = in_sizes[0] / 2;            // x is (B, 1, 2)
  const int G = (B + CHUNK - 1) / CHUNK;    // 256 for B=262144 (k2 needs G <= THREADS)

  k1<<<G, THREADS, 0, stream>>>(x, y, tl, w0, w1, w2, w3, b0, wb2, out, ws, B, G);
  k2<<<G, THREADS, 0, stream>>>(x, tl, w0, w1, w2, w3, b0, wb2, out, ws, B, G);
}